// Round 1
// baseline (276.436 us; speedup 1.0000x reference)
//
#include <hip/hip_runtime.h>
#include <stdint.h>

#define BB 4
#define TT 2048
#define DD 1024
#define NX (BB*TT*DD)          /* 8388608 x elements   */
#define NW (DD*DD)             /* 1048576 per W        */
#define SCALE 0.022097086912079608f   /* 1/sqrt(2048) */

typedef short v8s __attribute__((ext_vector_type(8)));
typedef float v4f __attribute__((ext_vector_type(4)));

__device__ __forceinline__ short f2bf(float f) {
    union { float f; uint32_t u; } x; x.f = f;
    uint32_t r = x.u + 0x7fffu + ((x.u >> 16) & 1u);   // RNE, finite inputs
    return (short)(r >> 16);
}
__device__ __forceinline__ float bf2f(short s) {
    union { uint32_t u; float f; } x; x.u = ((uint32_t)(uint16_t)s) << 16;
    return x.f;
}

// ---------------------------------------------------------------- convert
// dst = [ xb (NX) | Wqb (NW) | Wkb (NW) | Wvb (NW) ] bf16
__global__ void k_convert(const float* __restrict__ x, const float* __restrict__ Wq,
                          const float* __restrict__ Wk, const float* __restrict__ Wv,
                          short* __restrict__ dst) {
    int i = blockIdx.x * 256 + threadIdx.x;   // exactly (NX+3*NW)/4 threads
    size_t base = (size_t)i * 4;
    const float* src; size_t off;
    if (base < NX)               { src = x;  off = base; }
    else if (base < NX + NW)     { src = Wq; off = base - NX; }
    else if (base < NX + 2*(size_t)NW) { src = Wk; off = base - NX - NW; }
    else                         { src = Wv; off = base - NX - 2*(size_t)NW; }
    float4 f = *(const float4*)(src + off);
    short4 h; h.x = f2bf(f.x); h.y = f2bf(f.y); h.z = f2bf(f.z); h.w = f2bf(f.w);
    *(short4*)(dst + base) = h;
}

// ---------------------------------------------------------------- rowsum init
// rowsum[b*2048+i] = count of fully-masked k-tiles * 128 = (15 - i/128)*128
__global__ void k_init(float* __restrict__ rowsum) {
    int g = blockIdx.x * 256 + threadIdx.x;
    if (g < BB * TT) rowsum[g] = (float)((15 - ((g & 2047) >> 7)) * 128);
}

// ---------------------------------------------------------------- QKV GEMM
// C[m,n] = sum_d A[m,d]*W[n,d];  A=xb [8192,1024], W row-major [1024,1024]
// which: 0->q, 1->k (natural [m][e]), 2->v transposed vt[b][e][t]
__global__ __launch_bounds__(256) void k_qkv(const short* __restrict__ xb,
                                             const short* __restrict__ wb,
                                             short* __restrict__ q,
                                             short* __restrict__ k,
                                             short* __restrict__ vt) {
    int which = blockIdx.z;
    const short* A  = xb;
    const short* Bm = wb + (size_t)which * NW;
    int m0 = blockIdx.x * 128, n0 = blockIdx.y * 128;
    __shared__ short As[128][72];
    __shared__ short Bs[128][72];
    int tid = threadIdx.x, lane = tid & 63, wave = tid >> 6;
    int wm = (wave >> 1) * 64, wn = (wave & 1) * 64;
    int lr = lane & 15, lq = lane >> 4;
    v4f acc[4][4];
    for (int i = 0; i < 4; i++) for (int j = 0; j < 4; j++) acc[i][j] = (v4f){0.f,0.f,0.f,0.f};

    for (int d0 = 0; d0 < 1024; d0 += 64) {
        #pragma unroll
        for (int i = 0; i < 4; i++) {
            int s = i * 256 + tid, r = s >> 3, c8 = s & 7;
            *(uint4*)&As[r][c8*8] = *(const uint4*)(A  + (size_t)(m0 + r) * 1024 + d0 + c8*8);
            *(uint4*)&Bs[r][c8*8] = *(const uint4*)(Bm + (size_t)(n0 + r) * 1024 + d0 + c8*8);
        }
        __syncthreads();
        #pragma unroll
        for (int kk = 0; kk < 64; kk += 32) {
            v8s af[4], bf[4];
            #pragma unroll
            for (int i = 0; i < 4; i++) af[i] = *(const v8s*)&As[wm + i*16 + lr][kk + lq*8];
            #pragma unroll
            for (int j = 0; j < 4; j++) bf[j] = *(const v8s*)&Bs[wn + j*16 + lr][kk + lq*8];
            #pragma unroll
            for (int i = 0; i < 4; i++)
                #pragma unroll
                for (int j = 0; j < 4; j++)
                    acc[i][j] = __builtin_amdgcn_mfma_f32_16x16x32_bf16(af[i], bf[j], acc[i][j], 0, 0, 0);
        }
        __syncthreads();
    }
    short* outp = (which == 0) ? q : k;
    #pragma unroll
    for (int i = 0; i < 4; i++)
        #pragma unroll
        for (int j = 0; j < 4; j++)
            #pragma unroll
            for (int r = 0; r < 4; r++) {
                int row = m0 + wm + i*16 + lq*4 + r;     // m = b*2048+t
                int col = n0 + wn + j*16 + lr;           // e
                short hv = f2bf(acc[i][j][r]);
                if (which == 2) {
                    int bb = row >> 11, t = row & 2047;
                    vt[((size_t)bb << 21) + ((size_t)col << 11) + t] = hv;
                } else {
                    outp[(size_t)row * 1024 + col] = hv;
                }
            }
}

// ---------------------------------------------------------------- tile suffix sums
__global__ void k_ts1(const short* __restrict__ vt, float* __restrict__ TSpart) {
    int g = blockIdx.x * 256 + threadIdx.x;           // 4*16*1024 threads
    int b = g >> 14, jt = (g >> 10) & 15, e = g & 1023;
    const short* row = vt + ((size_t)b << 21) + ((size_t)e << 11) + jt * 128;
    float s = 0.f;
    #pragma unroll
    for (int c = 0; c < 16; c++) {
        uint4 u = *(const uint4*)(row + c * 8);
        const short* hp = (const short*)&u;
        #pragma unroll
        for (int z = 0; z < 8; z++) s += bf2f(hp[z]);
    }
    TSpart[g] = s;   // [b][jt][e]
}
__global__ void k_ts2(const float* __restrict__ TSpart, float* __restrict__ TS) {
    int g = blockIdx.x * 256 + threadIdx.x;           // 4*1024 threads
    int b = g >> 10, e = g & 1023;
    float acc = 0.f;
    TS[(size_t)(b * 17 + 16) * 1024 + e] = 0.f;
    for (int jt = 15; jt >= 0; jt--) {
        acc += TSpart[(size_t)(b * 16 + jt) * 1024 + e];
        TS[(size_t)(b * 17 + jt) * 1024 + e] = acc;   // sum over j >= jt*128
    }
}

// ---------------------------------------------------------------- S -> P kernel
// P[b][i][j] = exp(q_i.k_j * SCALE) for j<=i; 1.0 for in-tile j>i (diag tiles).
// rowsum += per-row sums (atomics; initialized with full-masked-tile counts).
__global__ __launch_bounds__(256) void k_pk(const short* __restrict__ qm,
                                            const short* __restrict__ km,
                                            short* __restrict__ P,
                                            float* __restrict__ rowsum) {
    int kt = blockIdx.x, qt = blockIdx.y, b = blockIdx.z;
    if (kt > qt) return;
    const short* A  = qm + ((size_t)b * 2048 + (size_t)qt * 128) * 1024;
    const short* Bm = km + ((size_t)b * 2048 + (size_t)kt * 128) * 1024;
    __shared__ short As[128][72];
    __shared__ short Bs[128][72];
    int tid = threadIdx.x, lane = tid & 63, wave = tid >> 6;
    int wm = (wave >> 1) * 64, wn = (wave & 1) * 64;
    int lr = lane & 15, lq = lane >> 4;
    v4f acc[4][4];
    for (int i = 0; i < 4; i++) for (int j = 0; j < 4; j++) acc[i][j] = (v4f){0.f,0.f,0.f,0.f};

    for (int d0 = 0; d0 < 1024; d0 += 64) {
        #pragma unroll
        for (int i = 0; i < 4; i++) {
            int s = i * 256 + tid, r = s >> 3, c8 = s & 7;
            *(uint4*)&As[r][c8*8] = *(const uint4*)(A  + (size_t)r * 1024 + d0 + c8*8);
            *(uint4*)&Bs[r][c8*8] = *(const uint4*)(Bm + (size_t)r * 1024 + d0 + c8*8);
        }
        __syncthreads();
        #pragma unroll
        for (int kk = 0; kk < 64; kk += 32) {
            v8s af[4], bf[4];
            #pragma unroll
            for (int i = 0; i < 4; i++) af[i] = *(const v8s*)&As[wm + i*16 + lr][kk + lq*8];
            #pragma unroll
            for (int j = 0; j < 4; j++) bf[j] = *(const v8s*)&Bs[wn + j*16 + lr][kk + lq*8];
            #pragma unroll
            for (int i = 0; i < 4; i++)
                #pragma unroll
                for (int j = 0; j < 4; j++)
                    acc[i][j] = __builtin_amdgcn_mfma_f32_16x16x32_bf16(af[i], bf[j], acc[i][j], 0, 0, 0);
        }
        __syncthreads();
    }
    short* Pb = P + ((size_t)b << 22);
    float rs[4][4];
    for (int i = 0; i < 4; i++) for (int r = 0; r < 4; r++) rs[i][r] = 0.f;
    #pragma unroll
    for (int i = 0; i < 4; i++)
        #pragma unroll
        for (int j = 0; j < 4; j++)
            #pragma unroll
            for (int r = 0; r < 4; r++) {
                int qi = qt * 128 + wm + i*16 + lq*4 + r;
                int kj = kt * 128 + wn + j*16 + lr;
                float p = (kj <= qi) ? __expf(acc[i][j][r] * SCALE) : 1.0f;
                Pb[(size_t)qi * 2048 + kj] = f2bf(p);
                rs[i][r] += p;
            }
    #pragma unroll
    for (int m = 1; m < 16; m <<= 1)
        #pragma unroll
        for (int i = 0; i < 4; i++)
            #pragma unroll
            for (int r = 0; r < 4; r++) rs[i][r] += __shfl_xor(rs[i][r], m);
    if (lr == 0)
        #pragma unroll
        for (int i = 0; i < 4; i++)
            #pragma unroll
            for (int r = 0; r < 4; r++)
                atomicAdd(&rowsum[b * 2048 + qt * 128 + wm + i*16 + lq*4 + r], rs[i][r]);
}

// ---------------------------------------------------------------- PV kernel
// out[b][i][e] = ( sum_{j<(qt+1)*128} P[i][j]*v[j][e]  + TS[b][qt+1][e] ) / rowsum
__global__ __launch_bounds__(256) void k_pv(const short* __restrict__ P,
                                            const short* __restrict__ vt,
                                            const float* __restrict__ rowsum,
                                            const float* __restrict__ TS,
                                            float* __restrict__ out) {
    int et = blockIdx.x, qt = blockIdx.y, b = blockIdx.z;
    const short* A  = P  + ((size_t)b << 22) + (size_t)qt * 128 * 2048;  // rows i, ld 2048
    const short* Bm = vt + ((size_t)b << 21) + (size_t)et * 128 * 2048;  // rows e, ld 2048
    int kd = (qt + 1) * 128;
    __shared__ short As[128][72];
    __shared__ short Bs[128][72];
    int tid = threadIdx.x, lane = tid & 63, wave = tid >> 6;
    int wm = (wave >> 1) * 64, wn = (wave & 1) * 64;
    int lr = lane & 15, lq = lane >> 4;
    v4f acc[4][4];
    for (int i = 0; i < 4; i++) for (int j = 0; j < 4; j++) acc[i][j] = (v4f){0.f,0.f,0.f,0.f};

    for (int d0 = 0; d0 < kd; d0 += 64) {
        #pragma unroll
        for (int i = 0; i < 4; i++) {
            int s = i * 256 + tid, r = s >> 3, c8 = s & 7;
            *(uint4*)&As[r][c8*8] = *(const uint4*)(A  + (size_t)r * 2048 + d0 + c8*8);
            *(uint4*)&Bs[r][c8*8] = *(const uint4*)(Bm + (size_t)r * 2048 + d0 + c8*8);
        }
        __syncthreads();
        #pragma unroll
        for (int kk = 0; kk < 64; kk += 32) {
            v8s af[4], bf[4];
            #pragma unroll
            for (int i = 0; i < 4; i++) af[i] = *(const v8s*)&As[wm + i*16 + lr][kk + lq*8];
            #pragma unroll
            for (int j = 0; j < 4; j++) bf[j] = *(const v8s*)&Bs[wn + j*16 + lr][kk + lq*8];
            #pragma unroll
            for (int i = 0; i < 4; i++)
                #pragma unroll
                for (int j = 0; j < 4; j++)
                    acc[i][j] = __builtin_amdgcn_mfma_f32_16x16x32_bf16(af[i], bf[j], acc[i][j], 0, 0, 0);
        }
        __syncthreads();
    }
    const float* tsrow = TS + (size_t)(b * 17 + qt + 1) * 1024;
    #pragma unroll
    for (int i = 0; i < 4; i++)
        #pragma unroll
        for (int j = 0; j < 4; j++)
            #pragma unroll
            for (int r = 0; r < 4; r++) {
                int row = qt * 128 + wm + i*16 + lq*4 + r;
                int col = et * 128 + wn + j*16 + lr;
                float o = (acc[i][j][r] + tsrow[col]) / rowsum[b * 2048 + row];
                out[((size_t)(b * 2048 + row) << 10) + col] = o;
            }
}

// ---------------------------------------------------------------- launch
extern "C" void kernel_launch(void* const* d_in, const int* in_sizes, int n_in,
                              void* d_out, int out_size, void* d_ws, size_t ws_size,
                              hipStream_t stream) {
    const float* x  = (const float*)d_in[0];
    const float* Wq = (const float*)d_in[1];
    const float* Wk = (const float*)d_in[2];
    const float* Wv = (const float*)d_in[3];
    float* out = (float*)d_out;
    char* ws = (char*)d_ws;

    short* xb     = (short*)(ws + 0);            // 16,777,216 B
    short* wb     = (short*)(ws + 16777216);     //  6,291,456 B (Wq|Wk|Wv bf16)
    short* q      = (short*)(ws + 23068672);     // 16,777,216 B
    short* k      = (short*)(ws + 39845888);     // 16,777,216 B
    short* vt     = (short*)(ws + 56623104);     // 16,777,216 B  v transposed [b][e][t]
    short* P      = (short*)(ws + 73400320);     // 33,554,432 B
    float* rowsum = (float*)(ws + 106954752);    //     32,768 B
    float* TSpart = (float*)(ws + 106987520);    //    262,144 B
    float* TS     = (float*)(ws + 107249664);    //    278,528 B   total ~102.6 MB

    k_convert<<<11264, 256, 0, stream>>>(x, Wq, Wk, Wv, xb);
    k_init<<<32, 256, 0, stream>>>(rowsum);
    k_qkv<<<dim3(64, 8, 3), 256, 0, stream>>>(xb, wb, q, k, vt);
    k_ts1<<<256, 256, 0, stream>>>(vt, TSpart);
    k_ts2<<<16, 256, 0, stream>>>(TSpart, TS);
    k_pk<<<dim3(16, 16, 4), 256, 0, stream>>>(q, k, P, rowsum);
    k_pv<<<dim3(8, 16, 4), 256, 0, stream>>>(P, vt, rowsum, TS, out);
}

// Round 2
// 270.971 us; speedup vs baseline: 1.0202x; 1.0202x over previous
//
#include <hip/hip_runtime.h>
#include <stdint.h>

#define BB 4
#define TT 2048
#define DD 1024
#define NX (BB*TT*DD)          /* 8388608 x elements   */
#define NW (DD*DD)             /* 1048576 per W        */
#define SCALE 0.022097086912079608f   /* 1/sqrt(2048) */

typedef short v8s __attribute__((ext_vector_type(8)));
typedef float v4f __attribute__((ext_vector_type(4)));

typedef const void __attribute__((address_space(1))) *as1_cvp;
typedef void __attribute__((address_space(3))) *as3_vp;

__device__ __forceinline__ short f2bf(float f) {
    union { float f; uint32_t u; } x; x.f = f;
    uint32_t r = x.u + 0x7fffu + ((x.u >> 16) & 1u);   // RNE, finite inputs
    return (short)(r >> 16);
}
__device__ __forceinline__ float bf2f(short s) {
    union { uint32_t u; float f; } x; x.u = ((uint32_t)(uint16_t)s) << 16;
    return x.f;
}

// Async 16B global->LDS. lds dest must be wave-uniform base + lane*16.
__device__ __forceinline__ void gl_lds16(const short* g, const short* lds_wave_base) {
    __builtin_amdgcn_global_load_lds(
        (as1_cvp)(uintptr_t)(const void*)g,
        (as3_vp)(uint32_t)(uintptr_t)(const void*)lds_wave_base,
        16, 0, 0);
}

// Stage a 128x64-short tile (16KB) from gsrc (leading dim lda shorts) into
// lds[128*64], with XOR-8 chunk swizzle: LDS chunk (r,c) holds global chunk
// (r, c^(r&7)).  4 issues x 256 thr x 16B.
__device__ __forceinline__ void stage_tile(const short* __restrict__ gsrc, int lda,
                                           short* lds, int tid) {
    int wave = tid >> 6;
    #pragma unroll
    for (int is = 0; is < 4; is++) {
        int t = is * 256 + tid;          // 0..1023 : 16B chunk index
        int r = t >> 3, c = t & 7;
        int cg = c ^ (r & 7);            // swizzled global chunk
        const short* g = gsrc + (size_t)r * lda + cg * 8;
        const short* l = lds + is * 2048 + wave * 512;   // wave-uniform
        gl_lds16(g, l);
    }
}

// Fragment read honoring the swizzle: global chunk cg of row `row`.
__device__ __forceinline__ v8s frag_read(const short* lds, int row, int cg) {
    return *(const v8s*)(lds + row * 64 + ((cg ^ (row & 7)) << 3));
}

// ---------------------------------------------------------------- convert
__global__ void k_convert(const float* __restrict__ x, const float* __restrict__ Wq,
                          const float* __restrict__ Wk, const float* __restrict__ Wv,
                          short* __restrict__ dst) {
    int i = blockIdx.x * 256 + threadIdx.x;   // exactly (NX+3*NW)/4 threads
    size_t base = (size_t)i * 4;
    const float* src; size_t off;
    if (base < NX)               { src = x;  off = base; }
    else if (base < NX + NW)     { src = Wq; off = base - NX; }
    else if (base < NX + 2*(size_t)NW) { src = Wk; off = base - NX - NW; }
    else                         { src = Wv; off = base - NX - 2*(size_t)NW; }
    float4 f = *(const float4*)(src + off);
    short4 h; h.x = f2bf(f.x); h.y = f2bf(f.y); h.z = f2bf(f.z); h.w = f2bf(f.w);
    *(short4*)(dst + base) = h;
}

// ---------------------------------------------------------------- rowsum init
__global__ void k_init(float* __restrict__ rowsum) {
    int g = blockIdx.x * 256 + threadIdx.x;
    if (g < BB * TT) rowsum[g] = (float)((15 - ((g & 2047) >> 7)) * 128);
}

// ---------------------------------------------------------------- QKV GEMM
__global__ __launch_bounds__(256) void k_qkv(const short* __restrict__ xb,
                                             const short* __restrict__ wb,
                                             short* __restrict__ q,
                                             short* __restrict__ k,
                                             short* __restrict__ vt) {
    int which = blockIdx.z;
    const short* A  = xb;
    const short* Bm = wb + (size_t)which * NW;
    int m0 = blockIdx.x * 128, n0 = blockIdx.y * 128;
    __shared__ __align__(16) short As[128*64];
    __shared__ __align__(16) short Bs[128*64];
    int tid = threadIdx.x, lane = tid & 63, wave = tid >> 6;
    int wm = (wave >> 1) * 64, wn = (wave & 1) * 64;
    int lr = lane & 15, lq = lane >> 4;
    v4f acc[4][4];
    for (int i = 0; i < 4; i++) for (int j = 0; j < 4; j++) acc[i][j] = (v4f){0.f,0.f,0.f,0.f};

    for (int d0 = 0; d0 < 1024; d0 += 64) {
        stage_tile(A  + (size_t)m0 * 1024 + d0, 1024, As, tid);
        stage_tile(Bm + (size_t)n0 * 1024 + d0, 1024, Bs, tid);
        __syncthreads();
        #pragma unroll
        for (int kk = 0; kk < 2; kk++) {           // cg base 0 / 4
            v8s af[4], bf[4];
            #pragma unroll
            for (int i = 0; i < 4; i++) af[i] = frag_read(As, wm + i*16 + lr, kk*4 + lq);
            #pragma unroll
            for (int j = 0; j < 4; j++) bf[j] = frag_read(Bs, wn + j*16 + lr, kk*4 + lq);
            #pragma unroll
            for (int i = 0; i < 4; i++)
                #pragma unroll
                for (int j = 0; j < 4; j++)
                    acc[i][j] = __builtin_amdgcn_mfma_f32_16x16x32_bf16(af[i], bf[j], acc[i][j], 0, 0, 0);
        }
        __syncthreads();
    }
    short* outp = (which == 0) ? q : k;
    #pragma unroll
    for (int i = 0; i < 4; i++)
        #pragma unroll
        for (int j = 0; j < 4; j++)
            #pragma unroll
            for (int r = 0; r < 4; r++) {
                int row = m0 + wm + i*16 + lq*4 + r;     // m = b*2048+t
                int col = n0 + wn + j*16 + lr;           // e
                short hv = f2bf(acc[i][j][r]);
                if (which == 2) {
                    int bb = row >> 11, t = row & 2047;
                    vt[((size_t)bb << 21) + ((size_t)col << 11) + t] = hv;
                } else {
                    outp[(size_t)row * 1024 + col] = hv;
                }
            }
}

// ---------------------------------------------------------------- tile suffix sums
__global__ void k_ts1(const short* __restrict__ vt, float* __restrict__ TSpart) {
    int g = blockIdx.x * 256 + threadIdx.x;           // 4*16*1024 threads
    int b = g >> 14, jt = (g >> 10) & 15, e = g & 1023;
    const short* row = vt + ((size_t)b << 21) + ((size_t)e << 11) + jt * 128;
    float s = 0.f;
    #pragma unroll
    for (int c = 0; c < 16; c++) {
        uint4 u = *(const uint4*)(row + c * 8);
        const short* hp = (const short*)&u;
        #pragma unroll
        for (int z = 0; z < 8; z++) s += bf2f(hp[z]);
    }
    TSpart[g] = s;   // [b][jt][e]
}
__global__ void k_ts2(const float* __restrict__ TSpart, float* __restrict__ TS) {
    int g = blockIdx.x * 256 + threadIdx.x;           // 4*1024 threads
    int b = g >> 10, e = g & 1023;
    float acc = 0.f;
    TS[(size_t)(b * 17 + 16) * 1024 + e] = 0.f;
    for (int jt = 15; jt >= 0; jt--) {
        acc += TSpart[(size_t)(b * 16 + jt) * 1024 + e];
        TS[(size_t)(b * 17 + jt) * 1024 + e] = acc;   // sum over j >= jt*128
    }
}

// ---------------------------------------------------------------- S -> P kernel
__global__ __launch_bounds__(256) void k_pk(const short* __restrict__ qm,
                                            const short* __restrict__ km,
                                            short* __restrict__ P,
                                            float* __restrict__ rowsum) {
    int kt = blockIdx.x, qt = blockIdx.y, b = blockIdx.z;
    if (kt > qt) return;
    const short* A  = qm + ((size_t)b * 2048 + (size_t)qt * 128) * 1024;
    const short* Bm = km + ((size_t)b * 2048 + (size_t)kt * 128) * 1024;
    __shared__ __align__(16) short As[128*64];
    __shared__ __align__(16) short Bs[128*64];
    int tid = threadIdx.x, lane = tid & 63, wave = tid >> 6;
    int wm = (wave >> 1) * 64, wn = (wave & 1) * 64;
    int lr = lane & 15, lq = lane >> 4;
    v4f acc[4][4];
    for (int i = 0; i < 4; i++) for (int j = 0; j < 4; j++) acc[i][j] = (v4f){0.f,0.f,0.f,0.f};

    for (int d0 = 0; d0 < 1024; d0 += 64) {
        stage_tile(A  + d0, 1024, As, tid);
        stage_tile(Bm + d0, 1024, Bs, tid);
        __syncthreads();
        #pragma unroll
        for (int kk = 0; kk < 2; kk++) {
            v8s af[4], bf[4];
            #pragma unroll
            for (int i = 0; i < 4; i++) af[i] = frag_read(As, wm + i*16 + lr, kk*4 + lq);
            #pragma unroll
            for (int j = 0; j < 4; j++) bf[j] = frag_read(Bs, wn + j*16 + lr, kk*4 + lq);
            #pragma unroll
            for (int i = 0; i < 4; i++)
                #pragma unroll
                for (int j = 0; j < 4; j++)
                    acc[i][j] = __builtin_amdgcn_mfma_f32_16x16x32_bf16(af[i], bf[j], acc[i][j], 0, 0, 0);
        }
        __syncthreads();
    }
    short* Pb = P + ((size_t)b << 22);
    float rs[4][4];
    for (int i = 0; i < 4; i++) for (int r = 0; r < 4; r++) rs[i][r] = 0.f;
    #pragma unroll
    for (int i = 0; i < 4; i++)
        #pragma unroll
        for (int j = 0; j < 4; j++)
            #pragma unroll
            for (int r = 0; r < 4; r++) {
                int qi = qt * 128 + wm + i*16 + lq*4 + r;
                int kj = kt * 128 + wn + j*16 + lr;
                float p = (kj <= qi) ? __expf(acc[i][j][r] * SCALE) : 1.0f;
                Pb[(size_t)qi * 2048 + kj] = f2bf(p);
                rs[i][r] += p;
            }
    #pragma unroll
    for (int m = 1; m < 16; m <<= 1)
        #pragma unroll
        for (int i = 0; i < 4; i++)
            #pragma unroll
            for (int r = 0; r < 4; r++) rs[i][r] += __shfl_xor(rs[i][r], m);
    if (lr == 0)
        #pragma unroll
        for (int i = 0; i < 4; i++)
            #pragma unroll
            for (int r = 0; r < 4; r++)
                atomicAdd(&rowsum[b * 2048 + qt * 128 + wm + i*16 + lq*4 + r], rs[i][r]);
}

// ---------------------------------------------------------------- PV kernel
__global__ __launch_bounds__(256) void k_pv(const short* __restrict__ P,
                                            const short* __restrict__ vt,
                                            const float* __restrict__ rowsum,
                                            const float* __restrict__ TS,
                                            float* __restrict__ out) {
    int et = blockIdx.x, qt = 15 - blockIdx.y, b = blockIdx.z;  // big-K blocks first
    const short* A  = P  + ((size_t)b << 22) + (size_t)qt * 128 * 2048;  // rows i, ld 2048
    const short* Bm = vt + ((size_t)b << 21) + (size_t)et * 128 * 2048;  // rows e, ld 2048
    int kd = (qt + 1) * 128;
    __shared__ __align__(16) short As[128*64];
    __shared__ __align__(16) short Bs[128*64];
    int tid = threadIdx.x, lane = tid & 63, wave = tid >> 6;
    int wm = (wave >> 1) * 64, wn = (wave & 1) * 64;
    int lr = lane & 15, lq = lane >> 4;
    v4f acc[4][4];
    for (int i = 0; i < 4; i++) for (int j = 0; j < 4; j++) acc[i][j] = (v4f){0.f,0.f,0.f,0.f};

    for (int d0 = 0; d0 < kd; d0 += 64) {
        stage_tile(A  + d0, 2048, As, tid);
        stage_tile(Bm + d0, 2048, Bs, tid);
        __syncthreads();
        #pragma unroll
        for (int kk = 0; kk < 2; kk++) {
            v8s af[4], bf[4];
            #pragma unroll
            for (int i = 0; i < 4; i++) af[i] = frag_read(As, wm + i*16 + lr, kk*4 + lq);
            #pragma unroll
            for (int j = 0; j < 4; j++) bf[j] = frag_read(Bs, wn + j*16 + lr, kk*4 + lq);
            #pragma unroll
            for (int i = 0; i < 4; i++)
                #pragma unroll
                for (int j = 0; j < 4; j++)
                    acc[i][j] = __builtin_amdgcn_mfma_f32_16x16x32_bf16(af[i], bf[j], acc[i][j], 0, 0, 0);
        }
        __syncthreads();
    }
    const float* tsrow = TS + (size_t)(b * 17 + qt + 1) * 1024;
    #pragma unroll
    for (int i = 0; i < 4; i++)
        #pragma unroll
        for (int j = 0; j < 4; j++)
            #pragma unroll
            for (int r = 0; r < 4; r++) {
                int row = qt * 128 + wm + i*16 + lq*4 + r;
                int col = et * 128 + wn + j*16 + lr;
                float o = (acc[i][j][r] + tsrow[col]) / rowsum[b * 2048 + row];
                out[((size_t)(b * 2048 + row) << 10) + col] = o;
            }
}

// ---------------------------------------------------------------- launch
extern "C" void kernel_launch(void* const* d_in, const int* in_sizes, int n_in,
                              void* d_out, int out_size, void* d_ws, size_t ws_size,
                              hipStream_t stream) {
    const float* x  = (const float*)d_in[0];
    const float* Wq = (const float*)d_in[1];
    const float* Wk = (const float*)d_in[2];
    const float* Wv = (const float*)d_in[3];
    float* out = (float*)d_out;
    char* ws = (char*)d_ws;

    short* xb     = (short*)(ws + 0);            // 16,777,216 B
    short* wb     = (short*)(ws + 16777216);     //  6,291,456 B (Wq|Wk|Wv bf16)
    short* q      = (short*)(ws + 23068672);     // 16,777,216 B
    short* k      = (short*)(ws + 39845888);     // 16,777,216 B
    short* vt     = (short*)(ws + 56623104);     // 16,777,216 B  v transposed [b][e][t]
    short* P      = (short*)(ws + 73400320);     // 33,554,432 B
    float* rowsum = (float*)(ws + 106954752);    //     32,768 B
    float* TSpart = (float*)(ws + 106987520);    //    262,144 B
    float* TS     = (float*)(ws + 107249664);    //    278,528 B   total ~102.6 MB

    k_convert<<<11264, 256, 0, stream>>>(x, Wq, Wk, Wv, xb);
    k_init<<<32, 256, 0, stream>>>(rowsum);
    k_qkv<<<dim3(64, 8, 3), 256, 0, stream>>>(xb, wb, q, k, vt);
    k_ts1<<<256, 256, 0, stream>>>(vt, TSpart);
    k_ts2<<<16, 256, 0, stream>>>(TSpart, TS);
    k_pk<<<dim3(16, 16, 4), 256, 0, stream>>>(q, k, P, rowsum);
    k_pv<<<dim3(8, 16, 4), 256, 0, stream>>>(P, vt, rowsum, TS, out);
}

// Round 4
// 251.961 us; speedup vs baseline: 1.0971x; 1.0754x over previous
//
#include <hip/hip_runtime.h>
#include <stdint.h>

#define BB 4
#define TT 2048
#define DD 1024
#define NX (BB*TT*DD)          /* 8388608 x elements   */
#define NW (DD*DD)             /* 1048576 per W        */
#define SCALE 0.022097086912079608f   /* 1/sqrt(2048) */

typedef short v8s __attribute__((ext_vector_type(8)));
typedef float v4f __attribute__((ext_vector_type(4)));

typedef const void __attribute__((address_space(1))) *as1_cvp;
typedef void __attribute__((address_space(3))) *as3_vp;

__device__ __forceinline__ short f2bf(float f) {
    union { float f; uint32_t u; } x; x.f = f;
    uint32_t r = x.u + 0x7fffu + ((x.u >> 16) & 1u);   // RNE, finite inputs
    return (short)(r >> 16);
}
__device__ __forceinline__ float bf2f(short s) {
    union { uint32_t u; float f; } x; x.u = ((uint32_t)(uint16_t)s) << 16;
    return x.f;
}

// Async 16B global->LDS. lds dest must be wave-uniform base + lane*16.
__device__ __forceinline__ void gl_lds16(const short* g, const short* lds_wave_base) {
    __builtin_amdgcn_global_load_lds(
        (as1_cvp)(uintptr_t)(const void*)g,
        (as3_vp)(uint32_t)(uintptr_t)(const void*)lds_wave_base,
        16, 0, 0);
}

// Stage a 128x64-short tile (16KB) from gsrc (leading dim lda shorts) into
// lds[128*64], with XOR-8 chunk swizzle: LDS chunk (r,c) holds global chunk
// (r, c^(r&7)).  4 issues x 256 thr x 16B.
__device__ __forceinline__ void stage_tile(const short* __restrict__ gsrc, int lda,
                                           short* lds, int tid) {
    int wave = tid >> 6;
    #pragma unroll
    for (int is = 0; is < 4; is++) {
        int t = is * 256 + tid;          // 0..1023 : 16B chunk index
        int r = t >> 3, c = t & 7;
        int cg = c ^ (r & 7);            // swizzled global chunk
        const short* g = gsrc + (size_t)r * lda + cg * 8;
        const short* l = lds + is * 2048 + wave * 512;   // wave-uniform
        gl_lds16(g, l);
    }
}

// Fragment read honoring the swizzle: global chunk cg of row `row`.
__device__ __forceinline__ v8s frag_read(const short* lds, int row, int cg) {
    return *(const v8s*)(lds + row * 64 + ((cg ^ (row & 7)) << 3));
}

// 16-MFMA x2 inner compute for one staged 128x64 tile pair.
#define COMPUTE_TILE(Ac, Bc)                                                        \
    _Pragma("unroll")                                                               \
    for (int kk = 0; kk < 2; kk++) {                                                \
        v8s af[4], bf[4];                                                           \
        _Pragma("unroll")                                                           \
        for (int i = 0; i < 4; i++) af[i] = frag_read(Ac, wm + i*16 + lr, kk*4 + lq); \
        _Pragma("unroll")                                                           \
        for (int j = 0; j < 4; j++) bf[j] = frag_read(Bc, wn + j*16 + lr, kk*4 + lq); \
        _Pragma("unroll")                                                           \
        for (int i = 0; i < 4; i++)                                                 \
            _Pragma("unroll")                                                       \
            for (int j = 0; j < 4; j++)                                             \
                acc[i][j] = __builtin_amdgcn_mfma_f32_16x16x32_bf16(af[i], bf[j], acc[i][j], 0, 0, 0); \
    }

// ---------------------------------------------------------------- convert (+ rowsum init)
__global__ void k_convert(const float* __restrict__ x, const float* __restrict__ Wq,
                          const float* __restrict__ Wk, const float* __restrict__ Wv,
                          short* __restrict__ dst, float* __restrict__ rowsum) {
    int i = blockIdx.x * 256 + threadIdx.x;   // exactly (NX+3*NW)/4 threads
    if (i < BB * TT) rowsum[i] = (float)((15 - ((i & 2047) >> 7)) * 128);
    size_t base = (size_t)i * 4;
    const float* src; size_t off;
    if (base < NX)               { src = x;  off = base; }
    else if (base < NX + NW)     { src = Wq; off = base - NX; }
    else if (base < NX + 2*(size_t)NW) { src = Wk; off = base - NX - NW; }
    else                         { src = Wv; off = base - NX - 2*(size_t)NW; }
    float4 f = *(const float4*)(src + off);
    short4 h; h.x = f2bf(f.x); h.y = f2bf(f.y); h.z = f2bf(f.z); h.w = f2bf(f.w);
    *(short4*)(dst + base) = h;
}

// ---------------------------------------------------------------- QKV GEMM (dbuf, 1 barrier/iter)
__global__ __launch_bounds__(256) void k_qkv(const short* __restrict__ xb,
                                             const short* __restrict__ wb,
                                             short* __restrict__ q,
                                             short* __restrict__ k,
                                             short* __restrict__ vt) {
    int which = blockIdx.z;
    const short* Bm = wb + (size_t)which * NW;
    int m0 = blockIdx.x * 128, n0 = blockIdx.y * 128;
    __shared__ __align__(16) short SH[32768];   // A0|A1|B0|B1, 16KB each
    int tid = threadIdx.x, lane = tid & 63, wave = tid >> 6;
    int wm = (wave >> 1) * 64, wn = (wave & 1) * 64;
    int lr = lane & 15, lq = lane >> 4;
    v4f acc[4][4];
    for (int i = 0; i < 4; i++) for (int j = 0; j < 4; j++) acc[i][j] = (v4f){0.f,0.f,0.f,0.f};

    const short* Ag = xb + (size_t)m0 * 1024;
    const short* Bg = Bm + (size_t)n0 * 1024;
    stage_tile(Ag, 1024, SH, tid);
    stage_tile(Bg, 1024, SH + 16384, tid);
    for (int it = 0; it < 16; ++it) {
        __syncthreads();                       // drains cur-buffer loads
        int cur = (it & 1) * 8192;
        short* Ac = SH + cur;
        short* Bc = SH + 16384 + cur;
        if (it + 1 < 16) {                     // prefetch next tile pair
            int nxt = ((it + 1) & 1) * 8192;
            stage_tile(Ag + (it + 1) * 64, 1024, SH + nxt, tid);
            stage_tile(Bg + (it + 1) * 64, 1024, SH + 16384 + nxt, tid);
        }
        COMPUTE_TILE(Ac, Bc);
    }
    short* outp = (which == 0) ? q : k;
    #pragma unroll
    for (int i = 0; i < 4; i++)
        #pragma unroll
        for (int j = 0; j < 4; j++)
            #pragma unroll
            for (int r = 0; r < 4; r++) {
                int row = m0 + wm + i*16 + lq*4 + r;     // m = b*2048+t
                int col = n0 + wn + j*16 + lr;           // e
                short hv = f2bf(acc[i][j][r]);
                if (which == 2) {
                    int bb = row >> 11, t = row & 2047;
                    vt[((size_t)bb << 21) + ((size_t)col << 11) + t] = hv;
                } else {
                    outp[(size_t)row * 1024 + col] = hv;
                }
            }
}

// ---------------------------------------------------------------- tile suffix sums
__global__ void k_ts1(const short* __restrict__ vt, float* __restrict__ TSpart) {
    int g = blockIdx.x * 256 + threadIdx.x;           // 4*16*1024 threads
    int b = g >> 14, jt = (g >> 10) & 15, e = g & 1023;
    const short* row = vt + ((size_t)b << 21) + ((size_t)e << 11) + jt * 128;
    float s = 0.f;
    #pragma unroll
    for (int c = 0; c < 16; c++) {
        uint4 u = *(const uint4*)(row + c * 8);
        const short* hp = (const short*)&u;
        #pragma unroll
        for (int z = 0; z < 8; z++) s += bf2f(hp[z]);
    }
    TSpart[g] = s;   // [b][jt][e]
}
__global__ void k_ts2(const float* __restrict__ TSpart, float* __restrict__ TS) {
    int g = blockIdx.x * 256 + threadIdx.x;           // 4*1024 threads
    int b = g >> 10, e = g & 1023;
    float acc = 0.f;
    TS[(size_t)(b * 17 + 16) * 1024 + e] = 0.f;
    for (int jt = 15; jt >= 0; jt--) {
        acc += TSpart[(size_t)(b * 16 + jt) * 1024 + e];
        TS[(size_t)(b * 17 + jt) * 1024 + e] = acc;   // sum over j >= jt*128
    }
}

// ---------------------------------------------------------------- S -> P kernel (dbuf)
__global__ __launch_bounds__(256) void k_pk(const short* __restrict__ qm,
                                            const short* __restrict__ km,
                                            short* __restrict__ P,
                                            float* __restrict__ rowsum) {
    int kt = blockIdx.x, qt = blockIdx.y, b = blockIdx.z;
    if (kt > qt) return;
    const short* Ag = qm + ((size_t)b * 2048 + (size_t)qt * 128) * 1024;
    const short* Bg = km + ((size_t)b * 2048 + (size_t)kt * 128) * 1024;
    __shared__ __align__(16) short SH[32768];
    int tid = threadIdx.x, lane = tid & 63, wave = tid >> 6;
    int wm = (wave >> 1) * 64, wn = (wave & 1) * 64;
    int lr = lane & 15, lq = lane >> 4;
    v4f acc[4][4];
    for (int i = 0; i < 4; i++) for (int j = 0; j < 4; j++) acc[i][j] = (v4f){0.f,0.f,0.f,0.f};

    stage_tile(Ag, 1024, SH, tid);
    stage_tile(Bg, 1024, SH + 16384, tid);
    for (int it = 0; it < 16; ++it) {
        __syncthreads();
        int cur = (it & 1) * 8192;
        short* Ac = SH + cur;
        short* Bc = SH + 16384 + cur;
        if (it + 1 < 16) {
            int nxt = ((it + 1) & 1) * 8192;
            stage_tile(Ag + (it + 1) * 64, 1024, SH + nxt, tid);
            stage_tile(Bg + (it + 1) * 64, 1024, SH + 16384 + nxt, tid);
        }
        COMPUTE_TILE(Ac, Bc);
    }
    short* Pb = P + ((size_t)b << 22);
    float rs[4][4];
    for (int i = 0; i < 4; i++) for (int r = 0; r < 4; r++) rs[i][r] = 0.f;
    #pragma unroll
    for (int i = 0; i < 4; i++)
        #pragma unroll
        for (int j = 0; j < 4; j++)
            #pragma unroll
            for (int r = 0; r < 4; r++) {
                int qi = qt * 128 + wm + i*16 + lq*4 + r;
                int kj = kt * 128 + wn + j*16 + lr;
                float p = (kj <= qi) ? __expf(acc[i][j][r] * SCALE) : 1.0f;
                Pb[(size_t)qi * 2048 + kj] = f2bf(p);
                rs[i][r] += p;
            }
    #pragma unroll
    for (int m = 1; m < 16; m <<= 1)
        #pragma unroll
        for (int i = 0; i < 4; i++)
            #pragma unroll
            for (int r = 0; r < 4; r++) rs[i][r] += __shfl_xor(rs[i][r], m);
    if (lr == 0)
        #pragma unroll
        for (int i = 0; i < 4; i++)
            #pragma unroll
            for (int r = 0; r < 4; r++)
                atomicAdd(&rowsum[b * 2048 + qt * 128 + wm + i*16 + lq*4 + r], rs[i][r]);
}

// ---------------------------------------------------------------- PV kernel (dbuf)
__global__ __launch_bounds__(256) void k_pv(const short* __restrict__ P,
                                            const short* __restrict__ vt,
                                            const float* __restrict__ rowsum,
                                            const float* __restrict__ TS,
                                            float* __restrict__ out) {
    int et = blockIdx.x, qt = 15 - blockIdx.y, b = blockIdx.z;  // big-K blocks first
    const short* Ag = P  + ((size_t)b << 22) + (size_t)qt * 128 * 2048;  // rows i, ld 2048
    const short* Bg = vt + ((size_t)b << 21) + (size_t)et * 128 * 2048;  // rows e, ld 2048
    int iters = 2 * (qt + 1);   // kd/64 = (qt+1)*128/64
    __shared__ __align__(16) short SH[32768];
    int tid = threadIdx.x, lane = tid & 63, wave = tid >> 6;
    int wm = (wave >> 1) * 64, wn = (wave & 1) * 64;
    int lr = lane & 15, lq = lane >> 4;
    v4f acc[4][4];
    for (int i = 0; i < 4; i++) for (int j = 0; j < 4; j++) acc[i][j] = (v4f){0.f,0.f,0.f,0.f};

    stage_tile(Ag, 2048, SH, tid);
    stage_tile(Bg, 2048, SH + 16384, tid);
    for (int it = 0; it < iters; ++it) {
        __syncthreads();
        int cur = (it & 1) * 8192;
        short* Ac = SH + cur;
        short* Bc = SH + 16384 + cur;
        if (it + 1 < iters) {
            int nxt = ((it + 1) & 1) * 8192;
            stage_tile(Ag + (it + 1) * 64, 2048, SH + nxt, tid);
            stage_tile(Bg + (it + 1) * 64, 2048, SH + 16384 + nxt, tid);
        }
        COMPUTE_TILE(Ac, Bc);
    }
    const float* tsrow = TS + (size_t)(b * 17 + qt + 1) * 1024;
    #pragma unroll
    for (int i = 0; i < 4; i++)
        #pragma unroll
        for (int j = 0; j < 4; j++)
            #pragma unroll
            for (int r = 0; r < 4; r++) {
                int row = qt * 128 + wm + i*16 + lq*4 + r;
                int col = et * 128 + wn + j*16 + lr;
                float o = (acc[i][j][r] + tsrow[col]) / rowsum[b * 2048 + row];
                out[((size_t)(b * 2048 + row) << 10) + col] = o;
            }
}

// ---------------------------------------------------------------- launch
extern "C" void kernel_launch(void* const* d_in, const int* in_sizes, int n_in,
                              void* d_out, int out_size, void* d_ws, size_t ws_size,
                              hipStream_t stream) {
    const float* x  = (const float*)d_in[0];
    const float* Wq = (const float*)d_in[1];
    const float* Wk = (const float*)d_in[2];
    const float* Wv = (const float*)d_in[3];
    float* out = (float*)d_out;
    char* ws = (char*)d_ws;

    short* xb     = (short*)(ws + 0);            // 16,777,216 B
    short* wb     = (short*)(ws + 16777216);     //  6,291,456 B (Wq|Wk|Wv bf16)
    short* q      = (short*)(ws + 23068672);     // 16,777,216 B
    short* k      = (short*)(ws + 39845888);     // 16,777,216 B
    short* vt     = (short*)(ws + 56623104);     // 16,777,216 B  v transposed [b][e][t]
    short* P      = (short*)(ws + 73400320);     // 33,554,432 B
    float* rowsum = (float*)(ws + 106954752);    //     32,768 B
    float* TSpart = (float*)(ws + 106987520);    //    262,144 B
    float* TS     = (float*)(ws + 107249664);    //    278,528 B   total ~102.6 MB

    k_convert<<<11264, 256, 0, stream>>>(x, Wq, Wk, Wv, xb, rowsum);
    k_qkv<<<dim3(64, 8, 3), 256, 0, stream>>>(xb, wb, q, k, vt);
    k_ts1<<<256, 256, 0, stream>>>(vt, TSpart);
    k_ts2<<<16, 256, 0, stream>>>(TSpart, TS);
    k_pk<<<dim3(16, 16, 4), 256, 0, stream>>>(q, k, P, rowsum);
    k_pv<<<dim3(8, 16, 4), 256, 0, stream>>>(P, vt, rowsum, TS, out);
}